// Round 1
// baseline (66.016 us; speedup 1.0000x reference)
//
#include <hip/hip_runtime.h>
#include <hip/hip_bf16.h>
#include <math.h>

// AngularSymmetry: B=16, M=64, P=6 (lambda=+1,+1,+1,-1,-1,-1; ita=4; zeta=2,4,8,2,4,8)
//
// res[b,i,p] = 2^(1-zeta_p) * sum_{j,k} (1 + lambda_p*cos(theta_ijk))^zeta_p
//                                        * G[b,i,j]*G[b,i,k]*G[b,j,k]
// where G[b,x,y] = exp(-4*d[b,x,y]^2) * d_cutoff[b,x,y]      (ita=4 is constant,
// and exp(-4*sum_sq) separates into the three pairwise factors),
// theta = dot(vec_ij, vec_ik) / (d[b,i,j]*d[b,i,k] + 1e-5).
//
// One block per (b,i): 1024 blocks x 256 threads. G[b] staged in LDS (16KB),
// exp computed inline. Thread fixes k = t&63 (lane) -> stride-1 LDS reads of
// Gmat[j*64+k] (conflict-free); j is wave-uniform -> LDS broadcast.

#define BB 16
#define MM 64
#define PP 6

__global__ __launch_bounds__(256) void angsym_kernel(
    const float* __restrict__ d_cutoff,
    const float* __restrict__ d,
    const float* __restrict__ coords,
    float* __restrict__ out)
{
    __shared__ float Gmat[MM * MM];           // 16 KB: G[b,j,k]
    __shared__ float vx[MM], vy[MM], vz[MM];  // vec_ij components
    __shared__ float Rrow[MM];                // d[b,i,:]
    __shared__ float Grow[MM];                // G[b,i,:]
    __shared__ float red[4 * PP];

    const int blk = blockIdx.x;
    const int b = blk >> 6;
    const int i = blk & 63;
    const int t = threadIdx.x;

    const float* __restrict__ db = d + b * MM * MM;
    const float* __restrict__ cb = d_cutoff + b * MM * MM;

    // Stage G[b] into LDS: 4096 elements, 16 per thread, coalesced.
    #pragma unroll
    for (int s = 0; s < (MM * MM) / 256; ++s) {
        int idx = t + s * 256;
        float dv = db[idx];
        Gmat[idx] = expf(-4.0f * dv * dv) * cb[idx];
    }

    // Stage vec_ij and d-row i.
    if (t < MM) {
        const float* cc = coords + (b * MM) * 3;
        float cix = cc[i * 3 + 0], ciy = cc[i * 3 + 1], ciz = cc[i * 3 + 2];
        vx[t] = cix - cc[t * 3 + 0];
        vy[t] = ciy - cc[t * 3 + 1];
        vz[t] = ciz - cc[t * 3 + 2];
        Rrow[t] = db[i * MM + t];
    }
    __syncthreads();
    if (t < MM) Grow[t] = Gmat[i * MM + t];
    __syncthreads();

    // Thread: k fixed = lane, j = (t>>6) + 4*s.
    const int k  = t & 63;
    const int jb = t >> 6;
    const float vxk = vx[k], vyk = vy[k], vzk = vz[k];
    const float Rk  = Rrow[k];
    const float Gik = Grow[k];

    float a0 = 0.f, a1 = 0.f, a2 = 0.f, a3 = 0.f, a4 = 0.f, a5 = 0.f;

    #pragma unroll
    for (int s = 0; s < 16; ++s) {
        const int j = jb + (s << 2);
        float dot = vx[j] * vxk + vy[j] * vyk + vz[j] * vzk;
        float den = Rrow[j] * Rk + 1e-5f;
        float th  = dot / den;           // IEEE div; theta can be ~1e6
        float c   = cosf(th);            // accurate reduction needed
        float w   = Grow[j] * Gik * Gmat[j * MM + k];
        float u = 1.0f + c, v = 1.0f - c;
        float u2 = u * u,  v2 = v * v;
        float u4 = u2 * u2, v4 = v2 * v2;
        float u8 = u4 * u4, v8 = v4 * v4;
        a0 += u2 * w; a1 += u4 * w; a2 += u8 * w;
        a3 += v2 * w; a4 += v4 * w; a5 += v8 * w;
    }

    // Wave (64-lane) butterfly reduction for the 6 accumulators.
    #pragma unroll
    for (int off = 32; off > 0; off >>= 1) {
        a0 += __shfl_down(a0, off);
        a1 += __shfl_down(a1, off);
        a2 += __shfl_down(a2, off);
        a3 += __shfl_down(a3, off);
        a4 += __shfl_down(a4, off);
        a5 += __shfl_down(a5, off);
    }

    const int wave = t >> 6;
    const int lane = t & 63;
    if (lane == 0) {
        red[wave * PP + 0] = a0;
        red[wave * PP + 1] = a1;
        red[wave * PP + 2] = a2;
        red[wave * PP + 3] = a3;
        red[wave * PP + 4] = a4;
        red[wave * PP + 5] = a5;
    }
    __syncthreads();

    if (t < PP) {
        float s = red[t] + red[PP + t] + red[2 * PP + t] + red[3 * PP + t];
        // 2^(1-zeta): zeta = 2,4,8 -> 0.5, 0.125, 0.0078125 (repeated for lambda=-1)
        const float scale = (t % 3 == 0) ? 0.5f : ((t % 3 == 1) ? 0.125f : 0.0078125f);
        out[(b * MM + i) * PP + t] = s * scale;
    }
}

extern "C" void kernel_launch(void* const* d_in, const int* in_sizes, int n_in,
                              void* d_out, int out_size, void* d_ws, size_t ws_size,
                              hipStream_t stream) {
    const float* d_cutoff = (const float*)d_in[0];
    const float* d        = (const float*)d_in[1];
    const float* coords   = (const float*)d_in[2];
    float* out            = (float*)d_out;

    angsym_kernel<<<BB * MM, 256, 0, stream>>>(d_cutoff, d, coords, out);
}

// Round 2
// 64.708 us; speedup vs baseline: 1.0202x; 1.0202x over previous
//
#include <hip/hip_runtime.h>
#include <hip/hip_bf16.h>
#include <math.h>

// AngularSymmetry: B=16, M=64, P=6 (lambda=+1,+1,+1,-1,-1,-1; ita=4; zeta=2,4,8,2,4,8)
//
// res[b,i,p] = 2^(1-zeta_p) * sum_{j,k} (1 + lambda_p*cos(theta_ijk))^zeta_p
//                                        * A_j * A_k * G[b,j,k]
// where G[b,x,y] = exp(-4*d[b,x,y]^2) * d_cutoff[b,x,y]  (ita=4 const; the
// exp(-4*sum_sq) separates into the three pairwise factors), A_j = G[b,i,j],
// theta = dot(vec_ij, vec_ik) / (d[b,i,j]*d[b,i,k] + 1e-5).
//
// One block per (b,i): 1024 blocks x 256 threads.
//  - T[j,k] = A_j*A_k*G[j,k] staged in LDS -> single ds_read_b32 weight.
//  - (vx,vy,vz,R) packed float4 -> single ds_read_b128, wave-uniform in j.
//  - custom branchless cos: double Cody-Waite reduction (exact for |x|<2^23,
//    theta <= ~5e6 here since den >= 1e-5) + float minimax polys. Replaces
//    ocml cosf's branchy multi-path reduction.

#define BB 16
#define MM 64
#define PP 6

__device__ __forceinline__ float fast_cos(float x) {
    // Valid for |x| < 2^30. Reduction error ~ n * 6.1e-17 <= ~3e-10 here.
    double xd = (double)x;
    double fn = rint(xd * 0.63661977236758138243);        // x * 2/pi
    float  r  = (float)fma(-fn, 1.5707963267948966, xd);  // r in [-pi/4, pi/4]
    int    q  = ((int)fn) & 3;
    float  z  = r * r;
    // fdlibm k_sinf / k_cosf minimax kernels on [-pi/4, pi/4]
    float s = r + r * z * (-1.6666666641626524e-01f + z * (8.3333293858894632e-03f
              + z * (-1.9839334836096632e-04f + z * 2.7183114939898219e-06f)));
    float c = 1.0f + z * (-4.9999999725103100e-01f + z * (4.1666623323739063e-02f
              + z * (-1.3886763774609929e-03f + z * 2.4390448796277409e-05f)));
    // cos(r + q*pi/2): q=0:c, 1:-s, 2:-c, 3:s
    float mag = (q & 1) ? s : c;
    return __int_as_float(__float_as_int(mag) ^ (((q + 1) & 2) << 30));
}

__global__ __launch_bounds__(256) void angsym_kernel(
    const float* __restrict__ d_cutoff,
    const float* __restrict__ d,
    const float* __restrict__ coords,
    float* __restrict__ out)
{
    __shared__ float4 Vrow[MM];      // (vx, vy, vz, R_ij) for row i
    __shared__ float  Arow[MM];      // A_j = exp(-4 d_ij^2) * dc_ij
    __shared__ float  Tmat[MM * MM]; // A_j * A_k * G[j,k]
    __shared__ float  red[4 * PP];

    const int blk = blockIdx.x;
    const int b = blk >> 6;
    const int i = blk & 63;
    const int t = threadIdx.x;

    const float* __restrict__ db = d        + b * MM * MM;
    const float* __restrict__ cb = d_cutoff + b * MM * MM;

    // Phase 1: row-i quantities.
    if (t < MM) {
        const float* cc = coords + b * MM * 3;
        float dv = db[i * MM + t];
        Arow[t] = expf(-4.0f * dv * dv) * cb[i * MM + t];
        Vrow[t] = make_float4(cc[i * 3 + 0] - cc[t * 3 + 0],
                              cc[i * 3 + 1] - cc[t * 3 + 1],
                              cc[i * 3 + 2] - cc[t * 3 + 2],
                              dv);
    }
    __syncthreads();

    // Phase 2: build T[j,k] = A_j * A_k * G[j,k]. j wave-uniform, k = lane.
    #pragma unroll
    for (int s = 0; s < (MM * MM) / 256; ++s) {
        int idx = t + s * 256;
        int j = idx >> 6, k = idx & 63;
        float dv = db[idx];
        float g  = expf(-4.0f * dv * dv) * cb[idx];
        Tmat[idx] = g * Arow[j] * Arow[k];
    }
    __syncthreads();

    // Main loop: k fixed = lane, j = (t>>6) + 4*s (wave-uniform).
    const int k  = t & 63;
    const int jb = t >> 6;
    const float4 Vk = Vrow[k];

    float a0 = 0.f, a1 = 0.f, a2 = 0.f, a3 = 0.f, a4 = 0.f, a5 = 0.f;

    #pragma unroll
    for (int s = 0; s < 16; ++s) {
        const int j = jb + (s << 2);
        float4 Vj = Vrow[j];                       // ds_read_b128, broadcast
        float dot = Vj.x * Vk.x + Vj.y * Vk.y + Vj.z * Vk.z;
        float den = Vj.w * Vk.w + 1e-5f;
        float th  = dot / den;                     // IEEE div: match reference theta
        float c   = fast_cos(th);
        float w   = Tmat[j * MM + k];              // stride-1 over lanes
        float u = 1.0f + c, v = 1.0f - c;
        float u2 = u * u,  v2 = v * v;
        float u4 = u2 * u2, v4 = v2 * v2;
        float u8 = u4 * u4, v8 = v4 * v4;
        a0 += u2 * w; a1 += u4 * w; a2 += u8 * w;
        a3 += v2 * w; a4 += v4 * w; a5 += v8 * w;
    }

    // 64-lane wave reduction.
    #pragma unroll
    for (int off = 32; off > 0; off >>= 1) {
        a0 += __shfl_down(a0, off);
        a1 += __shfl_down(a1, off);
        a2 += __shfl_down(a2, off);
        a3 += __shfl_down(a3, off);
        a4 += __shfl_down(a4, off);
        a5 += __shfl_down(a5, off);
    }

    const int wave = t >> 6;
    const int lane = t & 63;
    if (lane == 0) {
        red[wave * PP + 0] = a0;
        red[wave * PP + 1] = a1;
        red[wave * PP + 2] = a2;
        red[wave * PP + 3] = a3;
        red[wave * PP + 4] = a4;
        red[wave * PP + 5] = a5;
    }
    __syncthreads();

    if (t < PP) {
        float s = red[t] + red[PP + t] + red[2 * PP + t] + red[3 * PP + t];
        // 2^(1-zeta): zeta = 2,4,8 -> 0.5, 0.125, 0.0078125 (repeated for lambda=-1)
        const float scale = (t % 3 == 0) ? 0.5f : ((t % 3 == 1) ? 0.125f : 0.0078125f);
        out[(b * MM + i) * PP + t] = s * scale;
    }
}

extern "C" void kernel_launch(void* const* d_in, const int* in_sizes, int n_in,
                              void* d_out, int out_size, void* d_ws, size_t ws_size,
                              hipStream_t stream) {
    const float* d_cutoff = (const float*)d_in[0];
    const float* d        = (const float*)d_in[1];
    const float* coords   = (const float*)d_in[2];
    float* out            = (float*)d_out;

    angsym_kernel<<<BB * MM, 256, 0, stream>>>(d_cutoff, d, coords, out);
}

// Round 3
// 63.881 us; speedup vs baseline: 1.0334x; 1.0130x over previous
//
#include <hip/hip_runtime.h>
#include <hip/hip_bf16.h>
#include <math.h>

// AngularSymmetry: B=16, M=64, P=6 (lambda=+1,+1,+1,-1,-1,-1; ita=4; zeta=2,4,8,2,4,8)
//
// res[b,i,p] = 2^(1-zeta_p) * sum_{j,k} (1 + lambda_p*cos(theta_ijk))^zeta_p
//                                        * A_j * A_k * G[b,j,k]
// G[b,x,y] = exp(-4*d^2)*d_cutoff (ita=4 const; exp(-4*sum_sq) separates),
// A_j = G[b,i,j], theta = dot(vec_ij, vec_ik) / (d_ij*d_ik + 1e-5).
//
// j<->k symmetry: theta and A_j*A_k are exactly symmetric (bit-identical fp32);
// only G_jk is not. So
//   S = sum_{j<k} f(theta)*A_j*A_k*(G_jk+G_kj)  +  sum_j f(theta_jj)*A_j^2*G_jj
// Unordered pairs enumerated by the round-robin circle method: 63 rounds x 32
// disjoint pairs; each half-wave (32 lanes) covers rounds r = g + 8*s,
// s=0..7 (r=63 skipped) -> 8 main iterations/thread instead of 16.
//
// One block per (b,i): 1024 blocks x 256 threads.

#define BB 16
#define MM 64
#define PP 6

__device__ __forceinline__ float fast_cos(float x) {
    // Valid for |x| < 2^30 (theta <= ~5e6 here since den >= 1e-5).
    double xd = (double)x;
    double fn = rint(xd * 0.63661977236758138243);        // x * 2/pi
    float  r  = (float)fma(-fn, 1.5707963267948966, xd);  // r in [-pi/4, pi/4]
    int    q  = ((int)fn) & 3;
    float  z  = r * r;
    float s = r + r * z * (-1.6666666641626524e-01f + z * (8.3333293858894632e-03f
              + z * (-1.9839334836096632e-04f + z * 2.7183114939898219e-06f)));
    float c = 1.0f + z * (-4.9999999725103100e-01f + z * (4.1666623323739063e-02f
              + z * (-1.3886763774609929e-03f + z * 2.4390448796277409e-05f)));
    float mag = (q & 1) ? s : c;
    return __int_as_float(__float_as_int(mag) ^ (((q + 1) & 2) << 30));
}

__device__ __forceinline__ void accum_powers(float c, float w,
    float& a0, float& a1, float& a2, float& a3, float& a4, float& a5) {
    float u = 1.0f + c, v = 1.0f - c;
    float u2 = u * u,  v2 = v * v;
    float u4 = u2 * u2, v4 = v2 * v2;
    float u8 = u4 * u4, v8 = v4 * v4;
    a0 += u2 * w; a1 += u4 * w; a2 += u8 * w;
    a3 += v2 * w; a4 += v4 * w; a5 += v8 * w;
}

__global__ __launch_bounds__(256) void angsym_kernel(
    const float* __restrict__ d_cutoff,
    const float* __restrict__ d,
    const float* __restrict__ coords,
    float* __restrict__ out)
{
    __shared__ float4 Vrow[MM];      // (vx, vy, vz, R_ij) for row i
    __shared__ float  Arow[MM];      // A_j = G[b,i,j]
    __shared__ float  Tmat[MM * MM]; // A_j * A_k * G[j,k]
    __shared__ float  red[4 * PP];

    const int blk = blockIdx.x;
    const int b = blk >> 6;
    const int i = blk & 63;
    const int t = threadIdx.x;

    const float* __restrict__ db = d        + b * MM * MM;
    const float* __restrict__ cb = d_cutoff + b * MM * MM;

    // Phase 1: row-i quantities.
    if (t < MM) {
        const float* cc = coords + b * MM * 3;
        float dv = db[i * MM + t];
        Arow[t] = expf(-4.0f * dv * dv) * cb[i * MM + t];
        Vrow[t] = make_float4(cc[i * 3 + 0] - cc[t * 3 + 0],
                              cc[i * 3 + 1] - cc[t * 3 + 1],
                              cc[i * 3 + 2] - cc[t * 3 + 2],
                              dv);
    }
    __syncthreads();

    // Phase 2: T[j,k] = A_j * A_k * G[j,k].
    #pragma unroll
    for (int s = 0; s < (MM * MM) / 256; ++s) {
        int idx = t + s * 256;
        int j = idx >> 6, k = idx & 63;
        float dv = db[idx];
        float g  = expf(-4.0f * dv * dv) * cb[idx];
        Tmat[idx] = g * Arow[j] * Arow[k];
    }
    __syncthreads();

    // Main loop over unordered pairs: circle-method round-robin.
    // Half-wave g = t>>5 takes rounds r = g + 8*s; 32 lanes = 32 disjoint pairs.
    const int hl = t & 31;
    const int g  = t >> 5;

    float a0 = 0.f, a1 = 0.f, a2 = 0.f, a3 = 0.f, a4 = 0.f, a5 = 0.f;

    #pragma unroll
    for (int s = 0; s < 8; ++s) {
        const int r = g + (s << 3);
        if (r >= 63) continue;   // only g=7,s=7
        int p1, p2;
        if (hl == 0) { p1 = 63; p2 = r; }
        else {
            p1 = r + hl; if (p1 >= 63) p1 -= 63;
            p2 = r - hl; if (p2 < 0)   p2 += 63;
        }
        float4 Vj = Vrow[p1];
        float4 Vk = Vrow[p2];
        float dot = Vj.x * Vk.x + Vj.y * Vk.y + Vj.z * Vk.z;
        float den = Vj.w * Vk.w + 1e-5f;
        float c   = fast_cos(dot / den);
        float w   = Tmat[p1 * MM + p2] + Tmat[p2 * MM + p1]; // both orientations
        accum_powers(c, w, a0, a1, a2, a3, a4, a5);
    }

    // Diagonal terms j==k (wave 0 handles all 64).
    if (t < MM) {
        float4 Vd = Vrow[t];
        float dot = Vd.x * Vd.x + Vd.y * Vd.y + Vd.z * Vd.z;
        float den = Vd.w * Vd.w + 1e-5f;
        float c   = fast_cos(dot / den);
        float w   = Tmat[t * MM + t];
        accum_powers(c, w, a0, a1, a2, a3, a4, a5);
    }

    // 64-lane wave reduction.
    #pragma unroll
    for (int off = 32; off > 0; off >>= 1) {
        a0 += __shfl_down(a0, off);
        a1 += __shfl_down(a1, off);
        a2 += __shfl_down(a2, off);
        a3 += __shfl_down(a3, off);
        a4 += __shfl_down(a4, off);
        a5 += __shfl_down(a5, off);
    }

    const int wave = t >> 6;
    const int lane = t & 63;
    if (lane == 0) {
        red[wave * PP + 0] = a0;
        red[wave * PP + 1] = a1;
        red[wave * PP + 2] = a2;
        red[wave * PP + 3] = a3;
        red[wave * PP + 4] = a4;
        red[wave * PP + 5] = a5;
    }
    __syncthreads();

    if (t < PP) {
        float s = red[t] + red[PP + t] + red[2 * PP + t] + red[3 * PP + t];
        // 2^(1-zeta): zeta = 2,4,8 -> 0.5, 0.125, 0.0078125
        const float scale = (t % 3 == 0) ? 0.5f : ((t % 3 == 1) ? 0.125f : 0.0078125f);
        out[(b * MM + i) * PP + t] = s * scale;
    }
}

extern "C" void kernel_launch(void* const* d_in, const int* in_sizes, int n_in,
                              void* d_out, int out_size, void* d_ws, size_t ws_size,
                              hipStream_t stream) {
    const float* d_cutoff = (const float*)d_in[0];
    const float* d        = (const float*)d_in[1];
    const float* coords   = (const float*)d_in[2];
    float* out            = (float*)d_out;

    angsym_kernel<<<BB * MM, 256, 0, stream>>>(d_cutoff, d, coords, out);
}